// Round 2
// baseline (228.589 us; speedup 1.0000x reference)
//
#include <hip/hip_runtime.h>

// Sparsemax over rows: B=131072, D=256, fp32.
// TWO rows per 64-lane wave (ILP version). Each lane holds 4 contiguous
// elements of row A and 4 of row B. The max-reduce and the Michelot
// sum-reduce butterflies for the two rows are interleaved: the cross-lane
// shuffle latency (~20-40 cy/hop on the ds path) is the dominant serial
// cost per row, and two independent chains retire 2x work per chain
// traversal. Convergence (ballot count, scalar pipe) is checked BEFORE the
// sum butterfly so the final iteration costs no reduction; the loop exits
// when BOTH rows' active sets are stable.
// tau starts at max-1 (tight superset A0 = {z > max-1}, valid since
// tau* ∈ [max-1, max)): ~2-3 iterations for Gaussian rows.

#define D_COLS 256

// Native clang vector type: __builtin_nontemporal_store rejects
// HIP_vector_type<float,4>*, but accepts vectors of float.
typedef float fvec4 __attribute__((ext_vector_type(4)));

__global__ __launch_bounds__(256) void sparsemax_kernel(
    const float* __restrict__ x, float* __restrict__ out, int nrows) {
  const int wave = threadIdx.x >> 6;
  const int lane = threadIdx.x & 63;
  const int rowA = (blockIdx.x * 4 + wave) * 2;
  if (rowA >= nrows) return;
  const int rowB = (rowA + 1 < nrows) ? rowA + 1 : rowA;  // odd-tail: dup row

  fvec4 a = ((const fvec4*)(x + (size_t)rowA * D_COLS))[lane];
  fvec4 b = ((const fvec4*)(x + (size_t)rowB * D_COLS))[lane];

  // Interleaved row-max butterflies -> initial tau = max - 1.
  float ma = fmaxf(fmaxf(a.x, a.y), fmaxf(a.z, a.w));
  float mb = fmaxf(fmaxf(b.x, b.y), fmaxf(b.z, b.w));
  #pragma unroll
  for (int off = 32; off > 0; off >>= 1) {
    ma = fmaxf(ma, __shfl_xor(ma, off, 64));
    mb = fmaxf(mb, __shfl_xor(mb, off, 64));
  }

  float ta = ma - 1.0f, tb = mb - 1.0f;
  float pca = -1.0f, pcb = -1.0f;  // impossible counts => no break on iter 0

  for (int it = 0; it < 64; ++it) {
    unsigned long long a0 = __ballot(a.x > ta);
    unsigned long long a1 = __ballot(a.y > ta);
    unsigned long long a2 = __ballot(a.z > ta);
    unsigned long long a3 = __ballot(a.w > ta);
    unsigned long long b0 = __ballot(b.x > tb);
    unsigned long long b1 = __ballot(b.y > tb);
    unsigned long long b2 = __ballot(b.z > tb);
    unsigned long long b3 = __ballot(b.w > tb);
    float ca = (float)(__popcll(a0) + __popcll(a1) + __popcll(a2) + __popcll(a3));
    float cb = (float)(__popcll(b0) + __popcll(b1) + __popcll(b2) + __popcll(b3));

    const bool stA = (ca == pca);
    const bool stB = (cb == pcb);
    if (stA && stB) break;  // both active sets stable => both taus fixed

    float lsa = ((a.x > ta) ? a.x : 0.0f) + ((a.y > ta) ? a.y : 0.0f) +
                ((a.z > ta) ? a.z : 0.0f) + ((a.w > ta) ? a.w : 0.0f);
    float lsb = ((b.x > tb) ? b.x : 0.0f) + ((b.y > tb) ? b.y : 0.0f) +
                ((b.z > tb) ? b.z : 0.0f) + ((b.w > tb) ? b.w : 0.0f);
    #pragma unroll
    for (int off = 32; off > 0; off >>= 1) {
      lsa += __shfl_xor(lsa, off, 64);
      lsb += __shfl_xor(lsb, off, 64);
    }

    ta = stA ? ta : (lsa - 1.0f) / ca;  // freeze a converged row
    tb = stB ? tb : (lsb - 1.0f) / cb;
    pca = ca; pcb = cb;
  }

  fvec4 oa, ob;
  oa.x = fmaxf(a.x - ta, 0.0f); oa.y = fmaxf(a.y - ta, 0.0f);
  oa.z = fmaxf(a.z - ta, 0.0f); oa.w = fmaxf(a.w - ta, 0.0f);
  ob.x = fmaxf(b.x - tb, 0.0f); ob.y = fmaxf(b.y - tb, 0.0f);
  ob.z = fmaxf(b.z - tb, 0.0f); ob.w = fmaxf(b.w - tb, 0.0f);

  // Output is written once and never re-read by this kernel: nontemporal
  // stores skip L2 write-allocate, preserving cache for the streamed input.
  __builtin_nontemporal_store(oa, (fvec4*)(out + (size_t)rowA * D_COLS) + lane);
  if (rowB != rowA)
    __builtin_nontemporal_store(ob, (fvec4*)(out + (size_t)rowB * D_COLS) + lane);
}

extern "C" void kernel_launch(void* const* d_in, const int* in_sizes, int n_in,
                              void* d_out, int out_size, void* d_ws, size_t ws_size,
                              hipStream_t stream) {
  const float* x = (const float*)d_in[0];
  float* out = (float*)d_out;
  const int nrows = in_sizes[0] / D_COLS;
  const int blocks = (nrows + 7) / 8;  // 4 waves/block x 2 rows/wave = 8 rows
  sparsemax_kernel<<<blocks, 256, 0, stream>>>(x, out, nrows);
}

// Round 3
// 227.555 us; speedup vs baseline: 1.0045x; 1.0045x over previous
//
#include <hip/hip_runtime.h>

// Sparsemax over rows: B=131072, D=256, fp32.
// HALF-WAVE rows: row A lives in lanes 0-31, row B in lanes 32-63,
// 8 elements per lane (2x float4). One instruction stream serves BOTH rows:
//  - reduction butterflies are 5 hops within 32-lane groups
//    (__shfl_xor width=32; offsets <=16 lower to cheap DPP/swizzle),
//    vs 2x6 interleaved 64-wide hops in the previous 2-chain version;
//  - each __ballot covers both rows (row A = low 32 bits, row B = high 32),
//    per-row counts are scalar-pipe s_bcnt, overlapped with VALU;
//  - tau is per-lane (select row count by half).
// Michelot from the tight superset A0 = {z > max-1} (valid: tau* in
// [max-1, max)), ~2-3 iterations. Convergence check (scalar counts) runs
// BEFORE the sum butterfly so the last iteration costs no reduction; exits
// when BOTH rows' active sets are stable; a converged row's tau is frozen.

#define D_COLS 256

// Native clang vector type: __builtin_nontemporal_store rejects
// HIP_vector_type<float,4>*, but accepts vectors of float.
typedef float fvec4 __attribute__((ext_vector_type(4)));

__global__ __launch_bounds__(256) void sparsemax_kernel(
    const float* __restrict__ x, float* __restrict__ out, int nrows) {
  const int wave = threadIdx.x >> 6;
  const int lane = threadIdx.x & 63;
  const int half = lane >> 5;   // 0 -> row A, 1 -> row B
  const int hl = lane & 31;
  const int rowBase = (blockIdx.x * 4 + wave) * 2;
  if (rowBase >= nrows) return;
  int row = rowBase + half;
  const bool valid = (row < nrows);
  if (!valid) row = nrows - 1;  // odd-tail: hi half recomputes last row, no store

  // Lane hl of each half holds cols [4hl,4hl+4) and [128+4hl,128+4hl+4):
  // each load instruction is 16 B/lane over two contiguous 1 KB row-halves.
  const fvec4* rp = (const fvec4*)(x + (size_t)row * D_COLS);
  fvec4 v0 = rp[hl];
  fvec4 v1 = rp[hl + 32];

  // Row max within each 32-lane half -> initial tau = max - 1.
  float m = fmaxf(fmaxf(fmaxf(v0.x, v0.y), fmaxf(v0.z, v0.w)),
                  fmaxf(fmaxf(v1.x, v1.y), fmaxf(v1.z, v1.w)));
  #pragma unroll
  for (int off = 16; off > 0; off >>= 1) m = fmaxf(m, __shfl_xor(m, off, 32));

  float t = m - 1.0f;           // per-lane tau (uniform within each half)
  int pca = -1, pcb = -1;       // impossible counts => no break on iter 0

  for (int it = 0; it < 64; ++it) {
    // One ballot per element slot covers BOTH rows.
    unsigned long long b0 = __ballot(v0.x > t);
    unsigned long long b1 = __ballot(v0.y > t);
    unsigned long long b2 = __ballot(v0.z > t);
    unsigned long long b3 = __ballot(v0.w > t);
    unsigned long long b4 = __ballot(v1.x > t);
    unsigned long long b5 = __ballot(v1.y > t);
    unsigned long long b6 = __ballot(v1.z > t);
    unsigned long long b7 = __ballot(v1.w > t);
    const int ca = __popc((unsigned)b0) + __popc((unsigned)b1) +
                   __popc((unsigned)b2) + __popc((unsigned)b3) +
                   __popc((unsigned)b4) + __popc((unsigned)b5) +
                   __popc((unsigned)b6) + __popc((unsigned)b7);
    const int cb = __popc((unsigned)(b0 >> 32)) + __popc((unsigned)(b1 >> 32)) +
                   __popc((unsigned)(b2 >> 32)) + __popc((unsigned)(b3 >> 32)) +
                   __popc((unsigned)(b4 >> 32)) + __popc((unsigned)(b5 >> 32)) +
                   __popc((unsigned)(b6 >> 32)) + __popc((unsigned)(b7 >> 32));

    const bool stA = (ca == pca);
    const bool stB = (cb == pcb);
    if (stA && stB) break;  // both active sets stable => both taus fixed

    float ls = ((v0.x > t) ? v0.x : 0.0f) + ((v0.y > t) ? v0.y : 0.0f) +
               ((v0.z > t) ? v0.z : 0.0f) + ((v0.w > t) ? v0.w : 0.0f) +
               ((v1.x > t) ? v1.x : 0.0f) + ((v1.y > t) ? v1.y : 0.0f) +
               ((v1.z > t) ? v1.z : 0.0f) + ((v1.w > t) ? v1.w : 0.0f);
    #pragma unroll
    for (int off = 16; off > 0; off >>= 1) ls += __shfl_xor(ls, off, 32);

    const float cf = (float)(half ? cb : ca);
    const float tn = (ls - 1.0f) / cf;
    const bool stable = half ? stB : stA;  // freeze a converged row's tau
    t = stable ? t : tn;
    pca = ca; pcb = cb;
  }

  fvec4 o0, o1;
  o0.x = fmaxf(v0.x - t, 0.0f); o0.y = fmaxf(v0.y - t, 0.0f);
  o0.z = fmaxf(v0.z - t, 0.0f); o0.w = fmaxf(v0.w - t, 0.0f);
  o1.x = fmaxf(v1.x - t, 0.0f); o1.y = fmaxf(v1.y - t, 0.0f);
  o1.z = fmaxf(v1.z - t, 0.0f); o1.w = fmaxf(v1.w - t, 0.0f);

  if (valid) {
    // Written once, never re-read: nontemporal skips L2 write-allocate.
    fvec4* op = (fvec4*)(out + (size_t)row * D_COLS);
    __builtin_nontemporal_store(o0, op + hl);
    __builtin_nontemporal_store(o1, op + hl + 32);
  }
}

extern "C" void kernel_launch(void* const* d_in, const int* in_sizes, int n_in,
                              void* d_out, int out_size, void* d_ws, size_t ws_size,
                              hipStream_t stream) {
  const float* x = (const float*)d_in[0];
  float* out = (float*)d_out;
  const int nrows = in_sizes[0] / D_COLS;
  const int blocks = (nrows + 7) / 8;  // 4 waves/block x 2 rows/wave = 8 rows
  sparsemax_kernel<<<blocks, 256, 0, stream>>>(x, out, nrows);
}